// Round 1
// baseline (104.308 us; speedup 1.0000x reference)
//
#include <hip/hip_runtime.h>

#define B_    2048
#define T1_   31
#define D_    128
#define H_    128
#define NG_   512
#define MB_   16

typedef __attribute__((ext_vector_type(8))) short bf16x8;
typedef __attribute__((ext_vector_type(4))) float f32x4;

__device__ __forceinline__ unsigned short f2bf(float f) {
    union { float f; unsigned u; } v; v.f = f;
    unsigned r = v.u + 0x7fffu + ((v.u >> 16) & 1u);   // round-to-nearest-even
    return (unsigned short)(r >> 16);
}

__device__ __forceinline__ float sigf(float x) {
    return 1.0f / (1.0f + __expf(-x));
}

__device__ __forceinline__ float tanhf_(float x) {
    float ax = fabsf(x);
    float e  = __expf(2.0f * ax);
    float t  = 1.0f - 2.0f / (e + 1.0f);
    return copysignf(t, x);
}

// One block = 16 batches for all 31 timesteps. 512 threads = 8 waves.
// Wave w owns gates [w*64, w*64+64) with bf16 weight B-fragments in registers.
__global__ __launch_bounds__(512, 2) void enc_fused(
    const float* __restrict__ in,    // [B][31][128]
    const float* __restrict__ Wih,   // [512][128]
    const float* __restrict__ Whh,   // [512][128]
    const float* __restrict__ bih,   // [512]
    const float* __restrict__ bhh,   // [512]
    const float* __restrict__ aw,    // [287]
    float* __restrict__ outW,        // [B][31][128]
    float* __restrict__ outE)        // [B][31][128]
{
    const int tid  = threadIdx.x;
    const int lane = tid & 63;
    const int wv   = tid >> 6;       // wave 0..7
    const int b0   = blockIdx.x * MB_;

    __shared__ __align__(16) char Xs[MB_ * 512];   // bf16 [16][256], XOR-swizzled, 8 KB
    __shared__ float gS[MB_][NG_];                 // gates f32 (reused as x_score scratch), 32 KB
    __shared__ float attnS[MB_][D_];               // 8 KB
    __shared__ float wxv[T1_];

    if (tid < T1_) wxv[tid] = aw[2 * H_ + tid];
    __syncthreads();

    // ---------------- Phase A: x_score[b][d] = sum_t w_x[t] * in[b][t][d] ----
    const int dh = tid & 63;          // this thread covers d = 2*dh, 2*dh+1
    const int mg = tid >> 6;          // rows mg and mg+8 in phase A / wx phase
    const int d0 = 2 * dh;
    const float* pin0 = in + (size_t)(b0 + mg    ) * (T1_ * D_) + d0;
    const float* pin1 = in + (size_t)(b0 + mg + 8) * (T1_ * D_) + d0;

    float xs00 = 0.f, xs01 = 0.f, xs10 = 0.f, xs11 = 0.f;
    for (int t = 0; t < T1_; ++t) {
        float wt = wxv[t];
        float2 a = *(const float2*)(pin0 + t * D_);
        float2 b = *(const float2*)(pin1 + t * D_);
        xs00 += wt * a.x; xs01 += wt * a.y;
        xs10 += wt * b.x; xs11 += wt * b.y;
    }
    gS[mg    ][d0] = xs00; gS[mg    ][d0 + 1] = xs01;
    gS[mg + 8][d0] = xs10; gS[mg + 8][d0 + 1] = xs11;
    __syncthreads();

    // ---------------- softmax over d (128) : wave wv handles rows 2wv, 2wv+1 ---
    #pragma unroll
    for (int rr = 0; rr < 2; ++rr) {
        int r = 2 * wv + rr;
        float v0 = gS[r][lane], v1 = gS[r][lane + 64];
        float mx = fmaxf(v0, v1);
        #pragma unroll
        for (int o = 32; o > 0; o >>= 1) mx = fmaxf(mx, __shfl_xor(mx, o));
        float e0 = __expf(v0 - mx), e1 = __expf(v1 - mx);
        float s = e0 + e1;
        #pragma unroll
        for (int o = 32; o > 0; o >>= 1) s += __shfl_xor(s, o);
        float inv = 1.0f / s;
        attnS[r][lane]      = e0 * inv;
        attnS[r][lane + 64] = e1 * inv;
    }
    __syncthreads();

    const float a00 = attnS[mg    ][d0], a01 = attnS[mg    ][d0 + 1];
    const float a10 = attnS[mg + 8][d0], a11 = attnS[mg + 8][d0 + 1];

    // ---------------- weights -> register bf16 B-fragments ---------------------
    // B[k][n] = W[n][k]; lane l holds k = kf*32 + (l>>4)*8 + j (j=0..7),
    // n = wv*64 + nt*16 + (l&15).  K: 0..127 -> W_ih, 128..255 -> W_hh.
    bf16x8 bw[4][8];
    {
        const int nb = wv * 64;
        #pragma unroll
        for (int nt = 0; nt < 4; ++nt) {
            int n = nb + nt * 16 + (lane & 15);
            #pragma unroll
            for (int kf = 0; kf < 8; ++kf) {
                int kb = kf * 32 + (lane >> 4) * 8;
                bf16x8 v;
                #pragma unroll
                for (int j = 0; j < 8; ++j) {
                    int k = kb + j;
                    float f = (k < D_) ? Wih[n * D_ + k] : Whh[n * H_ + (k - D_)];
                    v[j] = (short)f2bf(f);
                }
                bw[nt][kf] = v;
            }
        }
    }

    // ---------------- biases + c state (update mapping: rows mg*2+i, cols d0..) -
    float2 bi2, bf2, bg2, bo2;
    bi2.x = bih[d0]          + bhh[d0];          bi2.y = bih[d0 + 1]          + bhh[d0 + 1];
    bf2.x = bih[D_ + d0]     + bhh[D_ + d0];     bf2.y = bih[D_ + d0 + 1]     + bhh[D_ + d0 + 1];
    bg2.x = bih[2*D_ + d0]   + bhh[2*D_ + d0];   bg2.y = bih[2*D_ + d0 + 1]   + bhh[2*D_ + d0 + 1];
    bo2.x = bih[3*D_ + d0]   + bhh[3*D_ + d0];   bo2.y = bih[3*D_ + d0 + 1]   + bhh[3*D_ + d0 + 1];
    float cs[2][2] = {{0.f, 0.f}, {0.f, 0.f}};

    // zero h-half of Xs (h = 0 initially)
    #pragma unroll
    for (int i = 0; i < 2; ++i) {
        int q = tid + i * 512;            // 0..1023, 64 u32 per row
        int m = q >> 6, u = q & 63;
        int bc = 256 + 4 * u;
        *(unsigned*)(Xs + m * 512 + (bc ^ ((m & 7) << 4))) = 0u;
    }

    // prefetch x for t = 0
    float2 x0 = *(const float2*)(pin0);
    float2 x1 = *(const float2*)(pin1);

    for (int t = 0; t < T1_; ++t) {
        // -------- wx = attn * x_t ; write f32 output + bf16 into Xs low half ----
        float wx00 = a00 * x0.x, wx01 = a01 * x0.y;
        float wx10 = a10 * x1.x, wx11 = a11 * x1.y;
        *(float2*)(outW + (size_t)((b0 + mg    ) * T1_ + t) * D_ + d0) = make_float2(wx00, wx01);
        *(float2*)(outW + (size_t)((b0 + mg + 8) * T1_ + t) * D_ + d0) = make_float2(wx10, wx11);

        unsigned u0 = (unsigned)f2bf(wx00) | ((unsigned)f2bf(wx01) << 16);
        unsigned u1 = (unsigned)f2bf(wx10) | ((unsigned)f2bf(wx11) << 16);
        int bc = 4 * dh;
        *(unsigned*)(Xs + mg * 512       + (bc ^ (( mg      & 7) << 4))) = u0;
        *(unsigned*)(Xs + (mg + 8) * 512 + (bc ^ (((mg + 8) & 7) << 4))) = u1;

        // prefetch next x_t (hides HBM/L3 latency under MFMA + update)
        if (t + 1 < T1_) {
            x0 = *(const float2*)(pin0 + (t + 1) * D_);
            x1 = *(const float2*)(pin1 + (t + 1) * D_);
        }
        __syncthreads();

        // -------- gates[16x512] = X[16x256] @ W^T, bf16 MFMA --------------------
        bf16x8 afr[8];
        {
            int row = lane & 15;
            int sw  = (row & 7) << 4;
            #pragma unroll
            for (int kf = 0; kf < 8; ++kf) {
                int bcol = kf * 64 + (lane >> 4) * 16;
                afr[kf] = *(const bf16x8*)(Xs + row * 512 + (bcol ^ sw));
            }
        }
        #pragma unroll
        for (int nt = 0; nt < 4; ++nt) {
            f32x4 acc = {0.f, 0.f, 0.f, 0.f};
            #pragma unroll
            for (int kf = 0; kf < 8; ++kf)
                acc = __builtin_amdgcn_mfma_f32_16x16x32_bf16(afr[kf], bw[nt][kf], acc, 0, 0, 0);
            // C layout: col = lane&15, row = (lane>>4)*4 + r
            int n    = wv * 64 + nt * 16 + (lane & 15);
            int mrow = (lane >> 4) * 4;
            #pragma unroll
            for (int r = 0; r < 4; ++r)
                gS[mrow + r][n] = acc[r];
        }
        __syncthreads();

        // -------- LSTM elementwise update: rows m = mg*2 + i, cols d0, d0+1 -----
        #pragma unroll
        for (int i = 0; i < 2; ++i) {
            int m = mg * 2 + i;
            const float* gr = &gS[m][0];
            float2 iv = *(const float2*)(gr + d0);
            float2 fv = *(const float2*)(gr + D_   + d0);
            float2 gv = *(const float2*)(gr + 2*D_ + d0);
            float2 ov = *(const float2*)(gr + 3*D_ + d0);

            float cn0 = sigf(fv.x + bf2.x) * cs[i][0] + sigf(iv.x + bi2.x) * tanhf_(gv.x + bg2.x);
            float cn1 = sigf(fv.y + bf2.y) * cs[i][1] + sigf(iv.y + bi2.y) * tanhf_(gv.y + bg2.y);
            cs[i][0] = cn0; cs[i][1] = cn1;
            float h0 = sigf(ov.x + bo2.x) * tanhf_(cn0);
            float h1 = sigf(ov.y + bo2.y) * tanhf_(cn1);

            *(float2*)(outE + (size_t)((b0 + m) * T1_ + t) * D_ + d0) = make_float2(h0, h1);

            // bf16 h into Xs high half for next step's MFMA
            unsigned hu = (unsigned)f2bf(h0) | ((unsigned)f2bf(h1) << 16);
            int bch = 256 + 4 * dh;
            *(unsigned*)(Xs + m * 512 + (bch ^ ((m & 7) << 4))) = hu;
        }
        // next iteration's X writes happen after this step's barrier-2; A-reads
        // of this step completed before barrier-2 -> two barriers per step.
    }
}

extern "C" void kernel_launch(void* const* d_in, const int* in_sizes, int n_in,
                              void* d_out, int out_size, void* d_ws, size_t ws_size,
                              hipStream_t stream) {
    const float* in  = (const float*)d_in[0];
    const float* Wih = (const float*)d_in[1];
    const float* Whh = (const float*)d_in[2];
    const float* bih = (const float*)d_in[3];
    const float* bhh = (const float*)d_in[4];
    const float* aw  = (const float*)d_in[5];
    // d_in[6] (attn_b) is mathematically dead: softmax is shift-invariant.

    float* outW = (float*)d_out;
    float* outE = outW + (size_t)B_ * T1_ * D_;

    enc_fused<<<dim3(B_ / MB_), dim3(512), 0, stream>>>(in, Wih, Whh, bih, bhh, aw, outW, outE);
}

// Round 5
// 69.956 us; speedup vs baseline: 1.4911x; 1.4911x over previous
//
#include <hip/hip_runtime.h>

#define B_   2048
#define T1_  31
#define D_   128
#define MB_  8

typedef __attribute__((ext_vector_type(8))) short bf16x8;
typedef __attribute__((ext_vector_type(4))) float f32x4;
typedef __attribute__((ext_vector_type(2))) float f32x2;

__device__ __forceinline__ unsigned cvt_pk_bf16(float lo, float hi) {
    unsigned r;
    asm("v_cvt_pk_bf16_f32 %0, %1, %2" : "=v"(r) : "v"(lo), "v"(hi));
    return r;
}
__device__ __forceinline__ unsigned short f2bf(float f) {
    union { float f; unsigned u; } v; v.f = f;
    unsigned r = v.u + 0x7fffu + ((v.u >> 16) & 1u);
    return (unsigned short)(r >> 16);
}
__device__ __forceinline__ float rcpf_(float x) { return __builtin_amdgcn_rcpf(x); }
__device__ __forceinline__ float sigf(float x)  { return rcpf_(1.0f + __expf(-x)); }
__device__ __forceinline__ float tanhf_(float x) {
    float ax = fabsf(x);
    float t  = 1.0f - 2.0f * rcpf_(__expf(2.0f * ax) + 1.0f);
    return copysignf(t, x);
}

// 256 blocks x 512 threads; block owns 8 batches for all 31 steps.
// Wave wv owns gate columns { s*128 + wv*16 + (lane&15) : s=0..3 } -> the MFMA
// accumulator holds i,f,g,o of one (row,col) in-register: no LDS gate round-trip.
__global__ __launch_bounds__(512, 2) void enc_fused(
    const float* __restrict__ in,    // [B][31][128]
    const float* __restrict__ Wih,   // [512][128]
    const float* __restrict__ Whh,   // [512][128]
    const float* __restrict__ bih,   // [512]
    const float* __restrict__ bhh,   // [512]
    const float* __restrict__ aw,    // [287]
    float* __restrict__ outW,        // [B][31][128]
    float* __restrict__ outE)        // [B][31][128]
{
    const int tid  = threadIdx.x;
    const int lane = tid & 63;
    const int wv   = tid >> 6;        // wave 0..7
    const int b0   = blockIdx.x * MB_;
    const int l15  = lane & 15;
    const int lq   = lane >> 4;

    // LDS: exactly 64 KB. Xw = 30 wx slots (bf16 [8][128], XOR-swizzled, 2 KB each);
    // wx[30] recycles slot 0 (written at t==1, after all t=0 reads). Hs = h dbuf.
    __shared__ __align__(16) char Xw[30 * MB_ * 256];   // 61440 B
    __shared__ __align__(16) char Hs[2 * MB_ * 256];    // 4096 B

    // ---------------- weight fragments -> registers (issued early) -------------
    // B[k][n]: lane holds k = kf*32 + lq*8 + j, n = s*128 + wv*16 + l15.
    bf16x8 bw[4][8];
    #pragma unroll
    for (int s = 0; s < 4; ++s) {
        int n = s * 128 + wv * 16 + l15;
        #pragma unroll
        for (int kf = 0; kf < 8; ++kf) {
            int kb = kf * 32 + lq * 8;
            const float* wp = (kf < 4) ? (Wih + n * D_ + kb) : (Whh + n * D_ + (kb - 128));
            float4 fa = *(const float4*)(wp);
            float4 fb = *(const float4*)(wp + 4);
            union { bf16x8 v; unsigned u[4]; } tmp;
            tmp.u[0] = cvt_pk_bf16(fa.x, fa.y);
            tmp.u[1] = cvt_pk_bf16(fa.z, fa.w);
            tmp.u[2] = cvt_pk_bf16(fb.x, fb.y);
            tmp.u[3] = cvt_pk_bf16(fb.z, fb.w);
            bw[s][kf] = tmp.v;
        }
    }
    const int col = wv * 16 + l15;
    const float bs0 = bih[col]           + bhh[col];
    const float bs1 = bih[128 + col]     + bhh[128 + col];
    const float bs2 = bih[256 + col]     + bhh[256 + col];
    const float bs3 = bih[384 + col]     + bhh[384 + col];

    // ---------------- phase A: x_score + softmax (all same-wave) ---------------
    const int mg = wv;                 // batch row this wave owns in staging
    const int dh = lane;
    const int d0 = 2 * dh;
    const float* pin = in + (size_t)(b0 + mg) * (T1_ * D_) + d0;

    float xs0 = 0.f, xs1 = 0.f;
    #pragma unroll
    for (int t = 0; t < T1_; ++t) {
        float wt = aw[2 * D_ + t];
        float2 a = *(const float2*)(pin + t * D_);
        xs0 = fmaf(wt, a.x, xs0);
        xs1 = fmaf(wt, a.y, xs1);
    }
    float* attnS = (float*)Xw;         // [8][128] overlay on slots 0-1 (pre-phase only)
    attnS[mg * 128 + d0]     = xs0;
    attnS[mg * 128 + d0 + 1] = xs1;

    float v0 = attnS[mg * 128 + lane];
    float v1 = attnS[mg * 128 + lane + 64];
    float mx = fmaxf(v0, v1);
    #pragma unroll
    for (int o = 32; o > 0; o >>= 1) mx = fmaxf(mx, __shfl_xor(mx, o));
    float e0 = __expf(v0 - mx), e1 = __expf(v1 - mx);
    float ss = e0 + e1;
    #pragma unroll
    for (int o = 32; o > 0; o >>= 1) ss += __shfl_xor(ss, o);
    float inv = 1.0f / ss;
    attnS[mg * 128 + lane]      = e0 * inv;
    attnS[mg * 128 + lane + 64] = e1 * inv;
    const float a0 = attnS[mg * 128 + d0];
    const float a1 = attnS[mg * 128 + d0 + 1];
    __syncthreads();                   // attn reads done before wx overwrites overlay

    // ---------------- wx pre-phase: all outW + wx bf16 staging -----------------
    const int wxbyte = (4 * dh) ^ (mg << 4);        // swizzled u32 position in row
    float* outWp = outW + (size_t)(b0 + mg) * (T1_ * D_) + d0;
    unsigned wx30 = 0;
    #pragma unroll
    for (int t = 0; t < T1_; ++t) {
        float2 xv = *(const float2*)(pin + t * D_);          // L3-hot re-read
        float w0 = a0 * xv.x, w1 = a1 * xv.y;
        f32x2 wsv; wsv[0] = w0; wsv[1] = w1;
        __builtin_nontemporal_store(wsv, (f32x2*)(outWp + t * D_));
        unsigned u = cvt_pk_bf16(w0, w1);
        if (t < 30) *(unsigned*)(Xw + t * 2048 + mg * 256 + wxbyte) = u;
        else        wx30 = u;
    }
    ((unsigned*)Hs)[tid]       = 0u;   // h(0) = 0, both buffers
    ((unsigned*)Hs)[tid + 512] = 0u;
    __syncthreads();

    // ---------------- recurrent loop: one barrier per step ---------------------
    const int arow = l15 & 7;          // A-frag row (rows 8-15 duplicate 0-7, discarded)
    const int asw  = arow << 4;
    bf16x8 wxfr[4], hfr[4];
    #pragma unroll
    for (int kf = 0; kf < 4; ++kf)
        wxfr[kf] = *(const bf16x8*)(Xw + arow * 256 + ((kf * 64 + lq * 16) ^ asw));

    // lane -> output rows rb, rb+1 after the shfl split (all 64 lanes active)
    const int rb = ((lane & 31) >> 4) * 4 + ((lane >> 5) << 1);
    float cs0 = 0.f, cs1 = 0.f;
    float* outE0 = outE + (size_t)(b0 + rb)     * (T1_ * D_) + col;
    float* outE1 = outE + (size_t)(b0 + rb + 1) * (T1_ * D_) + col;

    for (int t = 0; t < T1_; ++t) {
        const char* hp = Hs + (t & 1) * 2048 + arow * 256;
        #pragma unroll
        for (int kf = 0; kf < 4; ++kf)
            hfr[kf] = *(const bf16x8*)(hp + ((kf * 64 + lq * 16) ^ asw));

        if (t == 1)   // recycle slot 0 with wx[30]; all t=0 reads completed at barrier(0)
            *(unsigned*)(Xw + mg * 256 + wxbyte) = wx30;

        f32x4 acc[4];
        #pragma unroll
        for (int s = 0; s < 4; ++s) {
            f32x4 a_ = {0.f, 0.f, 0.f, 0.f};
            #pragma unroll
            for (int kf = 0; kf < 4; ++kf)
                a_ = __builtin_amdgcn_mfma_f32_16x16x32_bf16(wxfr[kf], bw[s][kf],     a_, 0, 0, 0);
            #pragma unroll
            for (int kf = 0; kf < 4; ++kf)
                a_ = __builtin_amdgcn_mfma_f32_16x16x32_bf16(hfr[kf],  bw[s][4 + kf], a_, 0, 0, 0);
            acc[s] = a_;
        }

        // prefetch next step's wx fragments (static data; hides under elementwise)
        if (t < 30) {
            int slot = (t + 1 == 30) ? 0 : (t + 1);
            #pragma unroll
            for (int kf = 0; kf < 4; ++kf)
                wxfr[kf] = *(const bf16x8*)(Xw + slot * 2048 + arow * 256 + ((kf * 64 + lq * 16) ^ asw));
        }

        // redistribute acc rows 2,3 to lanes 32-63: every lane handles rows rb, rb+1
        float gq0[4], gq1[4];
        #pragma unroll
        for (int s = 0; s < 4; ++s) {
            float h2 = __shfl_xor(acc[s][2], 32);
            float h3 = __shfl_xor(acc[s][3], 32);
            gq0[s] = (lane < 32) ? acc[s][0] : h2;
            gq1[s] = (lane < 32) ? acc[s][1] : h3;
        }

        float iv, fv, gv, ov, cn, hh;
        iv = gq0[0] + bs0; fv = gq0[1] + bs1; gv = gq0[2] + bs2; ov = gq0[3] + bs3;
        cn = sigf(fv) * cs0 + sigf(iv) * tanhf_(gv); cs0 = cn;
        hh = sigf(ov) * tanhf_(cn);
        __builtin_nontemporal_store(hh, outE0 + t * D_);
        unsigned short hb0 = f2bf(hh);

        iv = gq1[0] + bs0; fv = gq1[1] + bs1; gv = gq1[2] + bs2; ov = gq1[3] + bs3;
        cn = sigf(fv) * cs1 + sigf(iv) * tanhf_(gv); cs1 = cn;
        hh = sigf(ov) * tanhf_(cn);
        __builtin_nontemporal_store(hh, outE1 + t * D_);
        unsigned short hb1 = f2bf(hh);

        if (t < 30) {
            char* hw = Hs + ((t + 1) & 1) * 2048;
            *(unsigned short*)(hw + rb * 256       + ((2 * col) ^ (rb << 4)))       = hb0;
            *(unsigned short*)(hw + (rb + 1) * 256 + ((2 * col) ^ ((rb + 1) << 4))) = hb1;
        }
        __syncthreads();
    }
}

extern "C" void kernel_launch(void* const* d_in, const int* in_sizes, int n_in,
                              void* d_out, int out_size, void* d_ws, size_t ws_size,
                              hipStream_t stream) {
    const float* in  = (const float*)d_in[0];
    const float* Wih = (const float*)d_in[1];
    const float* Whh = (const float*)d_in[2];
    const float* bih = (const float*)d_in[3];
    const float* bhh = (const float*)d_in[4];
    const float* aw  = (const float*)d_in[5];
    // d_in[6] (attn_b) is mathematically dead: softmax is shift-invariant.

    float* outW = (float*)d_out;
    float* outE = outW + (size_t)B_ * T1_ * D_;

    enc_fused<<<dim3(B_ / MB_), dim3(512), 0, stream>>>(in, Wih, Whh, bih, bhh, aw, outW, outE);
}

// Round 6
// 55.164 us; speedup vs baseline: 1.8909x; 1.2681x over previous
//
#include <hip/hip_runtime.h>

#define B_   2048
#define T1_  31
#define D_   128
#define MB_  8

typedef __attribute__((ext_vector_type(8))) short bf16x8;
typedef __attribute__((ext_vector_type(4))) float f32x4;
typedef __attribute__((ext_vector_type(2))) float f32x2;

__device__ __forceinline__ unsigned cvt_pk_bf16(float lo, float hi) {
    unsigned r;
    asm("v_cvt_pk_bf16_f32 %0, %1, %2" : "=v"(r) : "v"(lo), "v"(hi));
    return r;
}
__device__ __forceinline__ unsigned short f2bf(float f) {
    union { float f; unsigned u; } v; v.f = f;
    unsigned r = v.u + 0x7fffu + ((v.u >> 16) & 1u);
    return (unsigned short)(r >> 16);
}
__device__ __forceinline__ float rcpf_(float x) { return __builtin_amdgcn_rcpf(x); }
__device__ __forceinline__ float sigf(float x)  { return rcpf_(1.0f + __expf(-x)); }
__device__ __forceinline__ float tanhf_(float x) {
    float ax = fabsf(x);
    float t  = 1.0f - 2.0f * rcpf_(__expf(2.0f * ax) + 1.0f);
    return copysignf(t, x);
}

// 256 blocks x 512 threads; block owns 8 batches for all 31 steps.
// Wave wv owns gate columns { s*128 + wv*16 + (lane&15) : s=0..3 } -> MFMA acc
// holds i,f,g,o of one (row,col) in-register. A-rows are 2x-replicated
// (arow = l15&7), so C rows 8-15 duplicate 0-7: lanes 32-63 read their OWN
// acc[2],acc[3] for rows rb=2,3/6,7 -> no cross-lane redistribute needed.
__global__ __launch_bounds__(512, 2) void enc_fused(
    const float* __restrict__ in,    // [B][31][128]
    const float* __restrict__ Wih,   // [512][128]
    const float* __restrict__ Whh,   // [512][128]
    const float* __restrict__ bih,   // [512]
    const float* __restrict__ bhh,   // [512]
    const float* __restrict__ aw,    // [287]
    float* __restrict__ outW,        // [B][31][128]
    float* __restrict__ outE)        // [B][31][128]
{
    const int tid  = threadIdx.x;
    const int lane = tid & 63;
    const int wv   = tid >> 6;        // wave 0..7
    const int b0   = blockIdx.x * MB_;
    const int l15  = lane & 15;
    const int lq   = lane >> 4;

    // LDS: exactly 64 KB. Xw = 30 wx slots (bf16 [8][128], XOR-swizzled, 2 KB each);
    // wx[30] recycles slot 0 (written at t==1, after all t=0 reads). Hs = h dbuf.
    __shared__ __align__(16) char Xw[30 * MB_ * 256];   // 61440 B
    __shared__ __align__(16) char Hs[2 * MB_ * 256];    // 4096 B

    // ---------------- weight fragments -> registers (issued early) -------------
    // B[k][n]: lane holds k = kf*32 + lq*8 + j, n = s*128 + wv*16 + l15.
    bf16x8 bw[4][8];
    #pragma unroll
    for (int s = 0; s < 4; ++s) {
        int n = s * 128 + wv * 16 + l15;
        #pragma unroll
        for (int kf = 0; kf < 8; ++kf) {
            int kb = kf * 32 + lq * 8;
            const float* wp = (kf < 4) ? (Wih + n * D_ + kb) : (Whh + n * D_ + (kb - 128));
            float4 fa = *(const float4*)(wp);
            float4 fb = *(const float4*)(wp + 4);
            union { bf16x8 v; unsigned u[4]; } tmp;
            tmp.u[0] = cvt_pk_bf16(fa.x, fa.y);
            tmp.u[1] = cvt_pk_bf16(fa.z, fa.w);
            tmp.u[2] = cvt_pk_bf16(fb.x, fb.y);
            tmp.u[3] = cvt_pk_bf16(fb.z, fb.w);
            bw[s][kf] = tmp.v;
        }
    }
    const int col = wv * 16 + l15;
    const float bs0 = bih[col]           + bhh[col];
    const float bs1 = bih[128 + col]     + bhh[128 + col];
    const float bs2 = bih[256 + col]     + bhh[256 + col];
    const float bs3 = bih[384 + col]     + bhh[384 + col];

    // ---------------- phase A: x_score + softmax (all same-wave) ---------------
    const int mg = wv;                 // batch row this wave owns in staging
    const int dh = lane;
    const int d0 = 2 * dh;
    const float* pin = in + (size_t)(b0 + mg) * (T1_ * D_) + d0;

    float xs0 = 0.f, xs1 = 0.f;
    #pragma unroll
    for (int t = 0; t < T1_; ++t) {
        float wt = aw[2 * D_ + t];
        float2 a = *(const float2*)(pin + t * D_);
        xs0 = fmaf(wt, a.x, xs0);
        xs1 = fmaf(wt, a.y, xs1);
    }
    float* attnS = (float*)Xw;         // [8][128] overlay on slots 0-1 (pre-phase only)
    attnS[mg * 128 + d0]     = xs0;
    attnS[mg * 128 + d0 + 1] = xs1;

    float v0 = attnS[mg * 128 + lane];
    float v1 = attnS[mg * 128 + lane + 64];
    float mx = fmaxf(v0, v1);
    #pragma unroll
    for (int o = 32; o > 0; o >>= 1) mx = fmaxf(mx, __shfl_xor(mx, o));
    float e0 = __expf(v0 - mx), e1 = __expf(v1 - mx);
    float ss = e0 + e1;
    #pragma unroll
    for (int o = 32; o > 0; o >>= 1) ss += __shfl_xor(ss, o);
    float inv = 1.0f / ss;
    attnS[mg * 128 + lane]      = e0 * inv;
    attnS[mg * 128 + lane + 64] = e1 * inv;
    const float a0 = attnS[mg * 128 + d0];
    const float a1 = attnS[mg * 128 + d0 + 1];
    __syncthreads();                   // attn reads done before wx overwrites overlay

    // ---------------- wx pre-phase: all outW + wx bf16 staging -----------------
    const int wxbyte = (4 * dh) ^ (mg << 4);        // swizzled u32 position in row
    float* outWp = outW + (size_t)(b0 + mg) * (T1_ * D_) + d0;
    unsigned wx30 = 0;
    #pragma unroll
    for (int t = 0; t < T1_; ++t) {
        float2 xv = *(const float2*)(pin + t * D_);          // L3-hot re-read
        float w0 = a0 * xv.x, w1 = a1 * xv.y;
        f32x2 wsv; wsv[0] = w0; wsv[1] = w1;
        __builtin_nontemporal_store(wsv, (f32x2*)(outWp + t * D_));
        unsigned u = cvt_pk_bf16(w0, w1);
        if (t < 30) *(unsigned*)(Xw + t * 2048 + mg * 256 + wxbyte) = u;
        else        wx30 = u;
    }
    ((unsigned*)Hs)[tid]       = 0u;   // h(0) = 0, both buffers
    ((unsigned*)Hs)[tid + 512] = 0u;
    __syncthreads();

    // ---------------- recurrent loop: one barrier per step ---------------------
    const int arow = l15 & 7;          // A-frag row (rows 8-15 replicate 0-7)
    const int asw  = arow << 4;
    bf16x8 wxfr[4];
    #pragma unroll
    for (int kf = 0; kf < 4; ++kf)
        wxfr[kf] = *(const bf16x8*)(Xw + arow * 256 + ((kf * 64 + lq * 16) ^ asw));

    // lane -> output rows rb, rb+1 (via C-row replication; no shfl needed)
    const int rb = ((lane & 31) >> 4) * 4 + ((lane >> 5) << 1);
    const bool hi32 = (lane >= 32);
    float cs0 = 0.f, cs1 = 0.f;
    float* outE0 = outE + (size_t)(b0 + rb)     * (T1_ * D_) + col;
    float* outE1 = outE + (size_t)(b0 + rb + 1) * (T1_ * D_) + col;

    // wx-part of gates for t=0 (independent of h)
    f32x4 accx[4];
    #pragma unroll
    for (int s = 0; s < 4; ++s) {
        f32x4 a_ = {0.f, 0.f, 0.f, 0.f};
        #pragma unroll
        for (int kf = 0; kf < 4; ++kf)
            a_ = __builtin_amdgcn_mfma_f32_16x16x32_bf16(wxfr[kf], bw[s][kf], a_, 0, 0, 0);
        accx[s] = a_;
    }

    for (int t = 0; t < T1_; ++t) {
        // h fragments for this step (the only post-barrier dependency)
        const char* hp = Hs + (t & 1) * 2048 + arow * 256;
        bf16x8 hfr[4];
        #pragma unroll
        for (int kf = 0; kf < 4; ++kf)
            hfr[kf] = *(const bf16x8*)(hp + ((kf * 64 + lq * 16) ^ asw));

        if (t == 1)   // recycle slot 0 with wx[30]; all t=0 reads completed at barrier(0)
            *(unsigned*)(Xw + mg * 256 + wxbyte) = wx30;

        // gates = accx (precomputed wx part) + h @ Whh^T
        f32x4 acc[4];
        #pragma unroll
        for (int s = 0; s < 4; ++s) {
            f32x4 a_ = accx[s];
            #pragma unroll
            for (int kf = 0; kf < 4; ++kf)
                a_ = __builtin_amdgcn_mfma_f32_16x16x32_bf16(hfr[kf], bw[s][4 + kf], a_, 0, 0, 0);
            acc[s] = a_;
        }

        // prefetch next step's wx fragments early (latency hides under elementwise)
        if (t < 30) {
            int slot = (t + 1 == 30) ? 0 : (t + 1);
            #pragma unroll
            for (int kf = 0; kf < 4; ++kf)
                wxfr[kf] = *(const bf16x8*)(Xw + slot * 2048 + arow * 256 + ((kf * 64 + lq * 16) ^ asw));
        }

        // row select via replication: lanes>=32 hold rows rb,rb+1 in acc[2],acc[3]
        float gq0[4], gq1[4];
        #pragma unroll
        for (int s = 0; s < 4; ++s) {
            gq0[s] = hi32 ? acc[s][2] : acc[s][0];
            gq1[s] = hi32 ? acc[s][3] : acc[s][1];
        }

        float iv, fv, gv, ov, cn, hh;
        iv = gq0[0] + bs0; fv = gq0[1] + bs1; gv = gq0[2] + bs2; ov = gq0[3] + bs3;
        cn = sigf(fv) * cs0 + sigf(iv) * tanhf_(gv); cs0 = cn;
        hh = sigf(ov) * tanhf_(cn);
        __builtin_nontemporal_store(hh, outE0 + t * D_);
        unsigned short hb0 = f2bf(hh);

        iv = gq1[0] + bs0; fv = gq1[1] + bs1; gv = gq1[2] + bs2; ov = gq1[3] + bs3;
        cn = sigf(fv) * cs1 + sigf(iv) * tanhf_(gv); cs1 = cn;
        hh = sigf(ov) * tanhf_(cn);
        __builtin_nontemporal_store(hh, outE1 + t * D_);
        unsigned short hb1 = f2bf(hh);

        if (t < 30) {
            char* hw = Hs + ((t + 1) & 1) * 2048;
            *(unsigned short*)(hw + rb * 256       + ((2 * col) ^ (rb << 4)))       = hb0;
            *(unsigned short*)(hw + (rb + 1) * 256 + ((2 * col) ^ ((rb + 1) << 4))) = hb1;

            // wx-part MFMAs for t+1: independent of h(t+1); fills barrier wait and
            // covers next step's hfr ds_read latency.
            #pragma unroll
            for (int s = 0; s < 4; ++s) {
                f32x4 a_ = {0.f, 0.f, 0.f, 0.f};
                #pragma unroll
                for (int kf = 0; kf < 4; ++kf)
                    a_ = __builtin_amdgcn_mfma_f32_16x16x32_bf16(wxfr[kf], bw[s][kf], a_, 0, 0, 0);
                accx[s] = a_;
            }
        }
        __syncthreads();
    }
}

extern "C" void kernel_launch(void* const* d_in, const int* in_sizes, int n_in,
                              void* d_out, int out_size, void* d_ws, size_t ws_size,
                              hipStream_t stream) {
    const float* in  = (const float*)d_in[0];
    const float* Wih = (const float*)d_in[1];
    const float* Whh = (const float*)d_in[2];
    const float* bih = (const float*)d_in[3];
    const float* bhh = (const float*)d_in[4];
    const float* aw  = (const float*)d_in[5];
    // d_in[6] (attn_b) is mathematically dead: softmax is shift-invariant.

    float* outW = (float*)d_out;
    float* outE = outW + (size_t)B_ * T1_ * D_;

    enc_fused<<<dim3(B_ / MB_), dim3(512), 0, stream>>>(in, Wih, Whh, bih, bhh, aw, outW, outE);
}